// Round 5
// baseline (512.485 us; speedup 1.0000x reference)
//
#include <hip/hip_runtime.h>
#include <stdint.h>

#define PRE_K   6000
#define POST_K  1000
#define CAP     8192      // candidate buffer per batch
#define BINS    1024
#define ROWS    6016      // 94*64, padded row count for NMS
#define CH      94        // ROWS/64 chunks
#define CHP     96        // padded row stride (uint2 words) for row-major maskR
#define NEGF    -1000000000.0f
#define IOU_EPS 16.0f     // f32 decision margin; f32 abs error bound ~2
#define KREG    12        // lazy forward-OR register slots per thread

// ---- helpers ----------------------------------------------------------------

__device__ __forceinline__ uint32_t orderf(float f) {
  uint32_t u = __float_as_uint(f);
  return (u & 0x80000000u) ? ~u : (u | 0x80000000u);
}

__device__ __forceinline__ int score_bin(float sc) {
  int bin = (int)floorf((sc + 12.0f) * ((float)BINS / 24.0f));
  return bin < 0 ? 0 : (bin > BINS - 1 ? BINS - 1 : bin);
}

__device__ __forceinline__ int bin_slot(int bin) {
  return ((bin & 15) << 6) | (bin >> 4);
}

// full double-precision decode, matching the float64 numpy reference
__device__ __forceinline__ void decode_box(
    const float* __restrict__ anchors, const float* __restrict__ deltas,
    const int* __restrict__ isz, int n, int b,
    double& x1, double& y1, double& x2, double& y2, bool& valid) {
  double ax1 = (double)anchors[4 * n + 0], ay1 = (double)anchors[4 * n + 1];
  double ax2 = (double)anchors[4 * n + 2], ay2 = (double)anchors[4 * n + 3];
  double aw = ax2 - ax1, ah = ay2 - ay1;
  double acx = ax1 + 0.5 * aw, acy = ay1 + 0.5 * ah;
  double tx = (double)deltas[4 * n + 0], ty = (double)deltas[4 * n + 1];
  double tw = (double)deltas[4 * n + 2], th = (double)deltas[4 * n + 3];
  tw = tw < -10.0 ? -10.0 : (tw > 10.0 ? 10.0 : tw);
  th = th < -10.0 ? -10.0 : (th > 10.0 ? 10.0 : th);
  double px = acx + tx * aw, py = acy + ty * ah;
  double pw = aw * exp(tw), ph = ah * exp(th);
  double H = (double)isz[2 * b + 0], W = (double)isz[2 * b + 1];
  double wm = W - 1.0, hm = H - 1.0;
  x1 = px - 0.5 * pw; y1 = py - 0.5 * ph;
  x2 = px + 0.5 * pw; y2 = py + 0.5 * ph;
  x1 = fmin(fmax(x1, 0.0), wm); x2 = fmin(fmax(x2, 0.0), wm);
  y1 = fmin(fmax(y1, 0.0), hm); y2 = fmin(fmax(y2, 0.0), hm);
  valid = (x2 - x1 >= 16.0) && (y2 - y1 >= 16.0);
}

// exact f64 suppression test (symmetric in its two rows)
__device__ __forceinline__ bool iou_exact(const double* __restrict__ tbox,
                                          const double* __restrict__ tarea,
                                          size_t ri, size_t ci) {
  const double* pr = &tbox[ri * 4];
  const double* pc = &tbox[ci * 4];
  double w = fmin(pr[2], pc[2]) - fmax(pr[0], pc[0]); w = w > 0.0 ? w : 0.0;
  double h = fmin(pr[3], pc[3]) - fmax(pr[1], pc[1]); h = h > 0.0 ? h : 0.0;
  double it = w * h;
  return it > 0.7 * (tarea[ri] + tarea[ci] - it + 1e-9);
}

// ---- kernels ----------------------------------------------------------------

// Decode + validity + LDS-privatized histogram.
__global__ void __launch_bounds__(256) k_score(const float* __restrict__ anchors,
                                               const int* __restrict__ bix,
                                               const int* __restrict__ isz,
                                               const float* __restrict__ logits,
                                               const float* __restrict__ deltas,
                                               float* __restrict__ scores,
                                               uint32_t* __restrict__ hist, int N) {
  const int SPAN = 4096;
  int start = blockIdx.x * SPAN;
  int end = start + SPAN < N ? start + SPAN : N;
  __shared__ uint32_t lh[2][BINS];
  for (int i = threadIdx.x; i < 2 * BINS; i += 256) ((uint32_t*)lh)[i] = 0u;
  __shared__ int s_b0, s_b1;
  if (threadIdx.x == 0) { s_b0 = bix[start]; s_b1 = bix[end - 1]; }
  __syncthreads();
  int b0 = s_b0, b1 = s_b1;

  for (int n = start + (int)threadIdx.x; n < end; n += 256) {
    int b = bix[n];
    double x1, y1, x2, y2; bool valid;
    decode_box(anchors, deltas, isz, n, b, x1, y1, x2, y2, valid);
    float sc = valid ? logits[n] : NEGF;
    scores[n] = sc;
    if (valid) {
      int bin = score_bin(sc);
      if (b == b0)      atomicAdd(&lh[0][bin], 1u);
      else if (b == b1) atomicAdd(&lh[1][bin], 1u);
      else              atomicAdd(&hist[b * BINS + bin_slot(bin)], 1u);
    }
  }
  __syncthreads();
  for (int bin = threadIdx.x; bin < BINS; bin += 256) {
    uint32_t c0 = lh[0][bin];
    if (c0) atomicAdd(&hist[b0 * BINS + bin_slot(bin)], c0);
    if (b1 != b0) {
      uint32_t c1 = lh[1][bin];
      if (c1) atomicAdd(&hist[b1 * BINS + bin_slot(bin)], c1);
    }
  }
}

// Block-aggregated compaction with fused threshold scan.
__global__ void __launch_bounds__(1024) k_compact(const float* __restrict__ scores,
                                                  const int* __restrict__ bix,
                                                  const uint32_t* __restrict__ hist,
                                                  uint32_t* __restrict__ cnt,
                                                  uint64_t* __restrict__ cand, int N) {
  const int SPAN = 8192;
  int start = blockIdx.x * SPAN;
  int end = start + SPAN < N ? start + SPAN : N;
  int t = threadIdx.x;
  __shared__ int s_b0, s_b1;
  __shared__ uint32_t sh[BINS];
  __shared__ int s_bs;
  __shared__ uint32_t lcnt[8], lbase[8];
  if (t == 0) { s_b0 = bix[start]; s_b1 = bix[end - 1]; }
  if (t < 8) lcnt[t] = 0u;
  __syncthreads();
  int b0 = s_b0, b1 = s_b1;

  uint32_t bs0 = 0, bs1 = 0;
  for (int pass = 0; pass < 2; pass++) {
    int b = pass == 0 ? b0 : b1;
    if (pass == 1 && b1 == b0) { bs1 = bs0; break; }
    if (t < BINS) sh[t] = hist[b * BINS + bin_slot(t)];
    if (t == 0) s_bs = 0;
    __syncthreads();
    for (int off = 1; off < BINS; off <<= 1) {
      uint32_t v = (t < BINS && t + off < BINS) ? sh[t + off] : 0u;
      __syncthreads();
      if (t < BINS) sh[t] += v;
      __syncthreads();
    }
    if (t < BINS && sh[t] >= PRE_K) atomicMax(&s_bs, t);
    __syncthreads();
    if (pass == 0) bs0 = (uint32_t)s_bs; else bs1 = (uint32_t)s_bs;
    __syncthreads();
  }

  bool     predv[8];
  uint64_t keyv[8];
  uint32_t lposv[8];
  int      bv[8];
  int nt = 0;
  for (int base = start; base < end; base += 1024, nt++) {
    int n = base + t;
    bool pred = false; int b = 0; uint64_t key = 0ull; uint32_t lp = 0u;
    if (n < end) {
      float sc = scores[n];
      if (sc > 0.5f * NEGF) {
        b = bix[n];
        uint32_t bs = (b == b0) ? bs0 : bs1;
        if ((uint32_t)score_bin(sc) >= bs) {
          pred = true;
          key = ((uint64_t)orderf(sc) << 32) | (uint64_t)(uint32_t)(~(uint32_t)n);
          lp = atomicAdd(&lcnt[b], 1u);
        }
      }
    }
    predv[nt] = pred; keyv[nt] = key; lposv[nt] = lp; bv[nt] = b;
  }
  __syncthreads();
  if (t < 8) {
    uint32_t c = lcnt[t];
    lbase[t] = c ? atomicAdd(&cnt[t], c) : 0u;
  }
  __syncthreads();
  for (int k = 0; k < nt; k++) {
    if (predv[k]) {
      uint32_t pos = lbase[bv[k]] + lposv[k];
      if (pos < CAP) cand[(size_t)bv[k] * CAP + pos] = keyv[k];
    }
  }
}

// Fused rank + place: block = (b, ic) ranks its 256 candidates against the
// full candidate list via LDS tiles, then decodes directly into row=rank.
__global__ void __launch_bounds__(256) k_rank_place(
    const uint64_t* __restrict__ cand, const uint32_t* __restrict__ cnt,
    const float* __restrict__ anchors, const float* __restrict__ deltas,
    const int* __restrict__ isz,
    double* __restrict__ tbox, double* __restrict__ tarea,
    float4* __restrict__ tboxf, float* __restrict__ tareaf,
    int* __restrict__ top_n, int* __restrict__ Cnum, int B) {
  int ic = blockIdx.x & 31;
  int b  = blockIdx.x >> 5;
  int t = threadIdx.x;
  int C = (int)min(cnt[b], (uint32_t)CAP);
  if (ic == 0 && t == 0) Cnum[b] = C < PRE_K ? C : PRE_K;
  if (ic * 256 >= C) return;
  const uint64_t* g = cand + (size_t)b * CAP;
  int i = ic * 256 + t;
  uint64_t ki = (i < C) ? g[i] : 0ull;

  __shared__ uint64_t tile[1024];
  int rank = 0;
  for (int base = 0; base < C; base += 1024) {
#pragma unroll
    for (int u = 0; u < 4; u++) {
      int j = base + u * 256 + t;
      tile[u * 256 + t] = (j < C) ? g[j] : 0ull;
    }
    __syncthreads();
    int lim = C - base < 1024 ? C - base : 1024;
    const ulonglong2* t2 = (const ulonglong2*)tile;
    int pairs = lim >> 1;
    int jj = 0;
    for (; jj + 4 <= pairs; jj += 4) {
      ulonglong2 v0 = t2[jj + 0], v1 = t2[jj + 1];
      ulonglong2 v2 = t2[jj + 2], v3 = t2[jj + 3];
      rank += (v0.x > ki) ? 1 : 0; rank += (v0.y > ki) ? 1 : 0;
      rank += (v1.x > ki) ? 1 : 0; rank += (v1.y > ki) ? 1 : 0;
      rank += (v2.x > ki) ? 1 : 0; rank += (v2.y > ki) ? 1 : 0;
      rank += (v3.x > ki) ? 1 : 0; rank += (v3.y > ki) ? 1 : 0;
    }
    for (; jj < pairs; jj++) {
      ulonglong2 v = t2[jj];
      rank += (v.x > ki) ? 1 : 0; rank += (v.y > ki) ? 1 : 0;
    }
    if (lim & 1) rank += (tile[lim - 1] > ki) ? 1 : 0;
    __syncthreads();
  }
  if (i >= C || rank >= PRE_K) return;

  int n = (int)(~(uint32_t)(ki & 0xFFFFFFFFull));
  double x1, y1, x2, y2; bool valid;
  decode_box(anchors, deltas, isz, n, b, x1, y1, x2, y2, valid);
  size_t row = (size_t)b * ROWS + rank;
  tbox[row * 4 + 0] = x1;
  tbox[row * 4 + 1] = y1;
  tbox[row * 4 + 2] = x2;
  tbox[row * 4 + 3] = y2;
  double ar = (x2 - x1) * (y2 - y1);
  tarea[row] = ar;
  tboxf[row] = make_float4((float)x1, (float)y1, (float)x2, (float)y2);
  tareaf[row] = (float)ar;
  top_n[b * PRE_K + rank] = n;
}

// Suppression bit tiles, upper triangle, two output layouts:
//  - near-diag band (d = cc-rc in {0,1,2}): maskB[((b*CH+rc)*3+d)*64+lane]
//    (coalesced; consumed by wave0's depth-2 prefetch in k_nms_reduce)
//  - far tiles (d >= 3): row-major maskR[(b*ROWS+row)*CHP + cc] (uint2),
//    each lane buffers 8 words and writes one aligned 64B run.
// Block = (g, rc, b), covers cc in [8g, 8g+8).
__global__ void __launch_bounds__(64) k_iou_mat(const float4* __restrict__ tboxf,
                                                const float* __restrict__ tareaf,
                                                const double* __restrict__ tbox,
                                                const double* __restrict__ tarea,
                                                const int* __restrict__ Cnum,
                                                uint32_t* __restrict__ maskB,
                                                uint32_t* __restrict__ maskR) {
  int g  = blockIdx.x;
  int rc = blockIdx.y;
  int b  = blockIdx.z;
  int C = Cnum[b];
  int nch = (C + 63) >> 6;
  if (rc >= nch) return;
  int cc_lo = g << 3;
  int cc_hi = (cc_lo + 8 < nch) ? cc_lo + 8 : nch;
  if (cc_lo >= nch || cc_hi <= rc) return;
  int lane = threadIdx.x;
  size_t bb = (size_t)b * ROWS;

  float4 rb4 = tboxf[bb + (size_t)rc * 64 + lane];
  float  sra = 0.7f * tareaf[bb + (size_t)rc * 64 + lane];
  __shared__ float4 cbx[64];
  __shared__ float  csa[64];

  uint2 fr[8];
#pragma unroll
  for (int u = 0; u < 8; u++) fr[u] = make_uint2(0u, 0u);
  bool any_far = false;

#pragma unroll
  for (int u = 0; u < 8; u++) {
    int cc = cc_lo + u;
    if (cc < rc || cc >= cc_hi) continue;
    __syncthreads();
    cbx[lane] = tboxf[bb + (size_t)cc * 64 + lane];
    csa[lane] = 0.7f * tareaf[bb + (size_t)cc * 64 + lane];
    __syncthreads();
    int d = cc - rc;
    bool isdiag = (d == 0);
    uint32_t r0 = 0u, r1 = 0u;
    for (int j = 0; j < 64; j++) {
      float4 c4 = cbx[j];
      float sca = csa[j];
      float iw = fminf(c4.z, rb4.z) - fmaxf(c4.x, rb4.x);
      float ih = fminf(c4.w, rb4.w) - fmaxf(c4.y, rb4.y);
      iw = fmaxf(iw, 0.0f); ih = fmaxf(ih, 0.0f);
      float inter = iw * ih;
      float diff = fmaf(1.7f, inter, -(sra + sca));
      bool gt = isdiag ? (j > lane) : true;
      bool sup = gt && (diff > IOU_EPS);
      if (gt && !sup && diff > -IOU_EPS) {
        sup = iou_exact(tbox, tarea, bb + (size_t)rc * 64 + lane,
                        bb + (size_t)cc * 64 + j);
      }
      if (sup) { if (j < 32) r0 |= 1u << j; else r1 |= 1u << (j & 31); }
    }
    if (d <= 2) {
      uint2* bp = (uint2*)maskB + (((size_t)b * CH + rc) * 3 + d) * 64;
      bp[lane] = make_uint2(r0, r1);
    } else {
      fr[u] = make_uint2(r0, r1);
      any_far = true;
    }
  }
  if (any_far) {
    size_t base = (bb + (size_t)rc * 64 + lane) * CHP + cc_lo;  // uint2 units
    uint4* dst = (uint4*)(maskR + base * 2);
    dst[0] = make_uint4(fr[0].x, fr[0].y, fr[1].x, fr[1].y);
    dst[1] = make_uint4(fr[2].x, fr[2].y, fr[3].x, fr[3].y);
    dst[2] = make_uint4(fr[4].x, fr[4].y, fr[5].x, fr[5].y);
    dst[3] = make_uint4(fr[6].x, fr[6].y, fr[7].x, fr[7].y);
  }
}

// Greedy resolve with forward-accumulated 64-bit suppression per chunk.
// acc[cc] = OR over already-kept rows j of mask(j, cc).
// Coverage of a row kept at iteration k over all cc > k:
//   cc = k+1, k+2 : wave0 ballots at iter k (band words, DEPTH-2 prefetched
//                   into parity register sets A/B -> no dependent-load stall)
//   cc >= k+3     : waves 1-3 ISSUE coalesced row-major loads at iter k+1,
//                   COMMIT via LDS atomicOr at iter k+2; read at >= k+3.
// One barrier per chunk. ~3 KB LDS.
__global__ void __launch_bounds__(256) k_nms_reduce(const uint32_t* __restrict__ maskB,
                                                    const uint32_t* __restrict__ maskR,
                                                    const double* __restrict__ tbox,
                                                    const int* __restrict__ Cnum,
                                                    const int* __restrict__ top_n,
                                                    const float* __restrict__ logits,
                                                    const float* __restrict__ deltas,
                                                    float* __restrict__ out, int B) {
  int b = blockIdx.x, t = threadIdx.x;
  int wave = t >> 6, lane = t & 63;
  int C = Cnum[b];
  int nch = (C + 63) >> 6;
  const uint2* Bb = (const uint2*)maskB + (size_t)b * CH * 3 * 64;
  const uint2* Rb = (const uint2*)maskR + (size_t)b * ROWS * CHP;
  size_t bb = (size_t)b * ROWS;

  __shared__ uint32_t acc[CH][2];      // forward-accumulated suppression bits
  __shared__ uint16_t kept[POST_K];    // kept rows, greedy order
  __shared__ uint16_t pend[2][64];     // rows kept at iteration c, parity c&1
  __shared__ int      npend[2];
  __shared__ uint64_t s_kept;

  for (int i = t; i < CH * 2; i += 256) ((uint32_t*)acc)[i] = 0u;
  if (t < 2) npend[t] = 0;
  __syncthreads();

  // wave0 depth-2 prefetch register sets (parity: A = even chunks, B = odd)
  uint2 dgA = make_uint2(0u,0u), pfA = make_uint2(0u,0u), qfA = make_uint2(0u,0u);
  uint2 dgB = make_uint2(0u,0u), pfB = make_uint2(0u,0u), qfB = make_uint2(0u,0u);
  if (wave == 0) {
    if (nch > 0) {
      dgA = Bb[((size_t)0 * 3 + 0) * 64 + lane];
      pfA = Bb[((size_t)0 * 3 + 1) * 64 + lane];
      qfA = Bb[((size_t)0 * 3 + 2) * 64 + lane];
    }
    if (nch > 1) {
      dgB = Bb[((size_t)1 * 3 + 0) * 64 + lane];
      pfB = Bb[((size_t)1 * 3 + 1) * 64 + lane];
      qfB = Bb[((size_t)1 * 3 + 2) * 64 + lane];
    }
  }

  // lazy pipeline state (waves 1-3): values loaded last iteration
  uint2 lz[KREG];
#pragma unroll
  for (int u = 0; u < KREG; u++) lz[u] = make_uint2(0u, 0u);
  int lz_total = 0, lz_cc0 = 0, lz_span = 1;

  int nkept = 0;
  for (int c = 0; c < nch; c++) {
    if (wave == 0) {
      // ---- select prefetched band words for chunk c ----
      uint2 dgv, pfv, qfv;
      if (c & 1) { dgv = dgB; pfv = pfB; qfv = qfB; }
      else       { dgv = dgA; pfv = pfA; qfv = qfA; }
      // ---- resolve chunk c (acc[c] complete by barrier discipline) ----
      int base = c << 6;
      uint64_t sup = (uint64_t)acc[c][0] | ((uint64_t)acc[c][1] << 32);
      int rem = C - base;
      if (rem < 64) sup |= ~((1ull << rem) - 1ull);
      uint64_t diag = (uint64_t)dgv.x | ((uint64_t)dgv.y << 32);
      uint64_t keptMask = 0ull;
      uint64_t alive = ~sup;
      uint64_t m = alive;
      while (m) {
        int i = __builtin_ctzll(m);
        keptMask |= 1ull << i;
        uint64_t d = (uint64_t)__shfl((long long)diag, i, 64);
        sup |= d | (1ull << i);
        m = alive & ~sup;
      }
      int allowed = POST_K - nkept;
      int pc2 = __popcll(keptMask);
      while (pc2 > allowed) {
        keptMask &= ~(1ull << (63 - __builtin_clzll(keptMask)));
        pc2--;
      }
      if (lane == 0) { s_kept = keptMask; npend[c & 1] = pc2; }
      bool mine = (keptMask >> lane) & 1ull;
      if (mine) {
        int pfx = __popcll(keptMask & ((1ull << lane) - 1ull));
        kept[nkept + pfx] = (uint16_t)(base + lane);
        pend[c & 1][pfx] = (uint16_t)(base + lane);
      }
      // ---- zero-latency ballots: kept rows of chunk c -> acc[c+1], acc[c+2] --
      if (c + 1 < nch) {
        uint32_t v0 = mine ? pfv.x : 0u, v1 = mine ? pfv.y : 0u;
        uint32_t w0 = mine ? qfv.x : 0u, w1 = mine ? qfv.y : 0u;
#pragma unroll
        for (int off = 32; off > 0; off >>= 1) {
          v0 |= (uint32_t)__shfl_xor((int)v0, off, 64);
          v1 |= (uint32_t)__shfl_xor((int)v1, off, 64);
          w0 |= (uint32_t)__shfl_xor((int)w0, off, 64);
          w1 |= (uint32_t)__shfl_xor((int)w1, off, 64);
        }
        if (lane == 0) {
          if (v0) atomicOr(&acc[c + 1][0], v0);
          if (v1) atomicOr(&acc[c + 1][1], v1);
          if (c + 2 < nch) {
            if (w0) atomicOr(&acc[c + 2][0], w0);
            if (w1) atomicOr(&acc[c + 2][1], w1);
          }
        }
      }
      // ---- issue depth-2 prefetch for chunk c+2 (same parity set) ----
      if (c + 2 < nch) {
        if (c & 1) {
          dgB = Bb[((size_t)(c + 2) * 3 + 0) * 64 + lane];
          pfB = Bb[((size_t)(c + 2) * 3 + 1) * 64 + lane];
          qfB = Bb[((size_t)(c + 2) * 3 + 2) * 64 + lane];
        } else {
          dgA = Bb[((size_t)(c + 2) * 3 + 0) * 64 + lane];
          pfA = Bb[((size_t)(c + 2) * 3 + 1) * 64 + lane];
          qfA = Bb[((size_t)(c + 2) * 3 + 2) * 64 + lane];
        }
      }
    } else {
      // ---- (1) COMMIT values loaded last iteration (targets cc >= c+1) ----
      if (lz_total > 0) {
#pragma unroll
        for (int u = 0; u < KREG; u++) {
          int it = (t - 64) + u * 192;
          if (it < lz_total) {
            int pi = it / lz_span;
            int cc = lz_cc0 + (it - pi * lz_span);
            if (lz[u].x) atomicOr(&acc[cc][0], lz[u].x);
            if (lz[u].y) atomicOr(&acc[cc][1], lz[u].y);
          }
        }
      }
      // ---- (2) ISSUE coalesced loads for rows kept at c-1 (cc >= c+2) ----
      int np = (c >= 1) ? npend[(c - 1) & 1] : 0;
      int cc0 = c + 2;
      int span = nch - cc0;
      if (np > 0 && span > 0) {
        int total = np * span;
#pragma unroll
        for (int u = 0; u < KREG; u++) {
          int it = (t - 64) + u * 192;
          uint2 v = make_uint2(0u, 0u);
          if (it < total) {
            int pi = it / span;
            int cc = cc0 + (it - pi * span);
            int row = (int)pend[(c - 1) & 1][pi];
            v = Rb[(size_t)row * CHP + cc];
          }
          lz[u] = v;
        }
        // overflow beyond KREG slots: immediate load+commit (rare)
        for (int it = (t - 64) + KREG * 192; it < total; it += 192) {
          int pi = it / span;
          int cc = cc0 + (it - pi * span);
          int row = (int)pend[(c - 1) & 1][pi];
          uint2 v = Rb[(size_t)row * CHP + cc];
          if (v.x) atomicOr(&acc[cc][0], v.x);
          if (v.y) atomicOr(&acc[cc][1], v.y);
        }
        lz_total = total < KREG * 192 ? total : KREG * 192;
        lz_cc0 = cc0; lz_span = span;
      } else {
        lz_total = 0;
      }
    }
    __syncthreads();

    int pc = __popcll(s_kept);
    nkept += pc;
    if (nkept >= POST_K) break;
  }

  // ---- fused output: block writes its batch's POST_K rows ----
  __syncthreads();
  int M_out = B * POST_K;
  for (int s2 = t; s2 < POST_K; s2 += 256) {
    float p0 = 0.f, p1 = 0.f, p2 = 0.f, p3 = 0.f;
    float ob = 0.f, d0f = 0.f, d1f = 0.f, d2f = 0.f, d3f = 0.f;
    float bi = -1.0f, okv = 0.0f;
    if (s2 < nkept) {
      int j = (int)kept[s2];
      int n = top_n[b * PRE_K + j];
      const double* p = &tbox[(bb + j) * 4];
      p0 = (float)p[0]; p1 = (float)p[1]; p2 = (float)p[2]; p3 = (float)p[3];
      ob = logits[n];
      d0f = deltas[4 * n + 0]; d1f = deltas[4 * n + 1];
      d2f = deltas[4 * n + 2]; d3f = deltas[4 * n + 3];
      bi = (float)b; okv = 1.0f;
    }
    int idx = b * POST_K + s2;
    out[idx * 4 + 0] = p0;
    out[idx * 4 + 1] = p1;
    out[idx * 4 + 2] = p2;
    out[idx * 4 + 3] = p3;
    out[4 * M_out + idx] = bi;
    out[5 * M_out + idx] = ob;
    out[6 * M_out + idx * 4 + 0] = d0f;
    out[6 * M_out + idx * 4 + 1] = d1f;
    out[6 * M_out + idx * 4 + 2] = d2f;
    out[6 * M_out + idx * 4 + 3] = d3f;
    out[10 * M_out + idx] = okv;
  }
}

// ---- launch -----------------------------------------------------------------

extern "C" void kernel_launch(void* const* d_in, const int* in_sizes, int n_in,
                              void* d_out, int out_size, void* d_ws, size_t ws_size,
                              hipStream_t stream) {
  const float* anchors = (const float*)d_in[0];
  const int*   bix     = (const int*)d_in[1];
  const int*   isz     = (const int*)d_in[2];
  const float* logits  = (const float*)d_in[3];
  const float* deltas  = (const float*)d_in[4];
  float* out = (float*)d_out;

  int N = in_sizes[1];
  int B = in_sizes[2] / 2;

  uintptr_t p = (uintptr_t)d_ws;
  double*   tbox   = (double*)p;    p += (size_t)B * ROWS * 4 * sizeof(double);
  double*   tarea  = (double*)p;    p += (size_t)B * ROWS * sizeof(double);
  uint64_t* cand   = (uint64_t*)p;  p += (size_t)B * CAP * sizeof(uint64_t);
  float*    scores = (float*)p;     p += (size_t)N * sizeof(float);
  uint32_t* hist   = (uint32_t*)p;  p += (size_t)B * BINS * sizeof(uint32_t);
  uint32_t* cnt    = (uint32_t*)p;  p += (size_t)B * sizeof(uint32_t);   // adjacent to hist
  int*      top_n  = (int*)p;       p += (size_t)B * PRE_K * sizeof(int);
  int*      Cnum   = (int*)p;       p += (size_t)B * sizeof(int);
  p = (p + 255) & ~(uintptr_t)255;
  uint32_t* maskB  = (uint32_t*)p;  p += (size_t)B * CH * 3 * 64 * 2 * sizeof(uint32_t);
  p = (p + 255) & ~(uintptr_t)255;
  uint32_t* maskR  = (uint32_t*)p;  p += (size_t)B * ROWS * CHP * 2 * sizeof(uint32_t);
  // f32 box mirror overlays `scores` (dead after k_compact)
  float4*   tboxf  = (float4*)scores;
  float*    tareaf = (float*)(scores + (size_t)B * ROWS * 4);
  (void)ws_size; (void)n_in; (void)out_size;

  hipMemsetAsync(hist, 0, (size_t)(B * BINS + B) * sizeof(uint32_t), stream);
  k_score<<<(N + 4095) / 4096, 256, 0, stream>>>(anchors, bix, isz, logits, deltas,
                                                 scores, hist, N);
  k_compact<<<(N + 8191) / 8192, 1024, 0, stream>>>(scores, bix, hist, cnt, cand, N);
  k_rank_place<<<B * 32, 256, 0, stream>>>(cand, cnt, anchors, deltas, isz,
                                           tbox, tarea, tboxf, tareaf,
                                           top_n, Cnum, B);
  dim3 iou_grid(12, CH, B);
  k_iou_mat<<<iou_grid, 64, 0, stream>>>(tboxf, tareaf, tbox, tarea, Cnum,
                                         maskB, maskR);
  k_nms_reduce<<<B, 256, 0, stream>>>(maskB, maskR, tbox, Cnum, top_n,
                                      logits, deltas, out, B);
}

// Round 6
// 384.164 us; speedup vs baseline: 1.3340x; 1.3340x over previous
//
#include <hip/hip_runtime.h>
#include <stdint.h>

#define PRE_K   6000
#define POST_K  1000
#define CAP     8192      // candidate buffer per batch
#define BINS    1024
#define ROWS    6016      // 94*64, padded row count for NMS
#define CH      94        // ROWS/64 chunks
#define JSPLIT  8         // k_rank comparison-range split
#define NEGF    -1000000000.0f
#define IOU_EPS 16.0f     // f32 decision margin; f32 abs error bound ~2
#define KREG    12        // lazy forward-OR register slots per thread

// ---- helpers ----------------------------------------------------------------

__device__ __forceinline__ uint32_t orderf(float f) {
  uint32_t u = __float_as_uint(f);
  return (u & 0x80000000u) ? ~u : (u | 0x80000000u);
}

__device__ __forceinline__ int score_bin(float sc) {
  int bin = (int)floorf((sc + 12.0f) * ((float)BINS / 24.0f));
  return bin < 0 ? 0 : (bin > BINS - 1 ? BINS - 1 : bin);
}

__device__ __forceinline__ int bin_slot(int bin) {
  return ((bin & 15) << 6) | (bin >> 4);
}

// Workgroup barrier that drains LDS (lgkmcnt) but NOT outstanding global
// loads (vmcnt). __syncthreads() would emit s_waitcnt vmcnt(0) before
// s_barrier, defeating cross-barrier prefetch pipelines. All cross-wave
// communication in k_nms_reduce is via LDS, so lgkmcnt(0) suffices.
__device__ __forceinline__ void wg_barrier_lds() {
  asm volatile("s_waitcnt lgkmcnt(0)" ::: "memory");
  __builtin_amdgcn_s_barrier();
  asm volatile("" ::: "memory");
}

// full double-precision decode, matching the float64 numpy reference
__device__ __forceinline__ void decode_box(
    const float* __restrict__ anchors, const float* __restrict__ deltas,
    const int* __restrict__ isz, int n, int b,
    double& x1, double& y1, double& x2, double& y2, bool& valid) {
  double ax1 = (double)anchors[4 * n + 0], ay1 = (double)anchors[4 * n + 1];
  double ax2 = (double)anchors[4 * n + 2], ay2 = (double)anchors[4 * n + 3];
  double aw = ax2 - ax1, ah = ay2 - ay1;
  double acx = ax1 + 0.5 * aw, acy = ay1 + 0.5 * ah;
  double tx = (double)deltas[4 * n + 0], ty = (double)deltas[4 * n + 1];
  double tw = (double)deltas[4 * n + 2], th = (double)deltas[4 * n + 3];
  tw = tw < -10.0 ? -10.0 : (tw > 10.0 ? 10.0 : tw);
  th = th < -10.0 ? -10.0 : (th > 10.0 ? 10.0 : th);
  double px = acx + tx * aw, py = acy + ty * ah;
  double pw = aw * exp(tw), ph = ah * exp(th);
  double H = (double)isz[2 * b + 0], W = (double)isz[2 * b + 1];
  double wm = W - 1.0, hm = H - 1.0;
  x1 = px - 0.5 * pw; y1 = py - 0.5 * ph;
  x2 = px + 0.5 * pw; y2 = py + 0.5 * ph;
  x1 = fmin(fmax(x1, 0.0), wm); x2 = fmin(fmax(x2, 0.0), wm);
  y1 = fmin(fmax(y1, 0.0), hm); y2 = fmin(fmax(y2, 0.0), hm);
  valid = (x2 - x1 >= 16.0) && (y2 - y1 >= 16.0);
}

// exact f64 suppression test (symmetric in its two rows)
__device__ __forceinline__ bool iou_exact(const double* __restrict__ tbox,
                                          const double* __restrict__ tarea,
                                          size_t ri, size_t ci) {
  const double* pr = &tbox[ri * 4];
  const double* pc = &tbox[ci * 4];
  double w = fmin(pr[2], pc[2]) - fmax(pr[0], pc[0]); w = w > 0.0 ? w : 0.0;
  double h = fmin(pr[3], pc[3]) - fmax(pr[1], pc[1]); h = h > 0.0 ? h : 0.0;
  double it = w * h;
  return it > 0.7 * (tarea[ri] + tarea[ci] - it + 1e-9);
}

// ---- kernels ----------------------------------------------------------------

// Decode + validity + LDS-privatized histogram.
__global__ void __launch_bounds__(256) k_score(const float* __restrict__ anchors,
                                               const int* __restrict__ bix,
                                               const int* __restrict__ isz,
                                               const float* __restrict__ logits,
                                               const float* __restrict__ deltas,
                                               float* __restrict__ scores,
                                               uint32_t* __restrict__ hist, int N) {
  const int SPAN = 4096;
  int start = blockIdx.x * SPAN;
  int end = start + SPAN < N ? start + SPAN : N;
  __shared__ uint32_t lh[2][BINS];
  for (int i = threadIdx.x; i < 2 * BINS; i += 256) ((uint32_t*)lh)[i] = 0u;
  __shared__ int s_b0, s_b1;
  if (threadIdx.x == 0) { s_b0 = bix[start]; s_b1 = bix[end - 1]; }
  __syncthreads();
  int b0 = s_b0, b1 = s_b1;

  for (int n = start + (int)threadIdx.x; n < end; n += 256) {
    int b = bix[n];
    double x1, y1, x2, y2; bool valid;
    decode_box(anchors, deltas, isz, n, b, x1, y1, x2, y2, valid);
    float sc = valid ? logits[n] : NEGF;
    scores[n] = sc;
    if (valid) {
      int bin = score_bin(sc);
      if (b == b0)      atomicAdd(&lh[0][bin], 1u);
      else if (b == b1) atomicAdd(&lh[1][bin], 1u);
      else              atomicAdd(&hist[b * BINS + bin_slot(bin)], 1u);
    }
  }
  __syncthreads();
  for (int bin = threadIdx.x; bin < BINS; bin += 256) {
    uint32_t c0 = lh[0][bin];
    if (c0) atomicAdd(&hist[b0 * BINS + bin_slot(bin)], c0);
    if (b1 != b0) {
      uint32_t c1 = lh[1][bin];
      if (c1) atomicAdd(&hist[b1 * BINS + bin_slot(bin)], c1);
    }
  }
}

// Block-aggregated compaction with fused threshold scan.
__global__ void __launch_bounds__(1024) k_compact(const float* __restrict__ scores,
                                                  const int* __restrict__ bix,
                                                  const uint32_t* __restrict__ hist,
                                                  uint32_t* __restrict__ cnt,
                                                  uint64_t* __restrict__ cand, int N) {
  const int SPAN = 8192;
  int start = blockIdx.x * SPAN;
  int end = start + SPAN < N ? start + SPAN : N;
  int t = threadIdx.x;
  __shared__ int s_b0, s_b1;
  __shared__ uint32_t sh[BINS];
  __shared__ int s_bs;
  __shared__ uint32_t lcnt[8], lbase[8];
  if (t == 0) { s_b0 = bix[start]; s_b1 = bix[end - 1]; }
  if (t < 8) lcnt[t] = 0u;
  __syncthreads();
  int b0 = s_b0, b1 = s_b1;

  uint32_t bs0 = 0, bs1 = 0;
  for (int pass = 0; pass < 2; pass++) {
    int b = pass == 0 ? b0 : b1;
    if (pass == 1 && b1 == b0) { bs1 = bs0; break; }
    if (t < BINS) sh[t] = hist[b * BINS + bin_slot(t)];
    if (t == 0) s_bs = 0;
    __syncthreads();
    for (int off = 1; off < BINS; off <<= 1) {
      uint32_t v = (t < BINS && t + off < BINS) ? sh[t + off] : 0u;
      __syncthreads();
      if (t < BINS) sh[t] += v;
      __syncthreads();
    }
    if (t < BINS && sh[t] >= PRE_K) atomicMax(&s_bs, t);
    __syncthreads();
    if (pass == 0) bs0 = (uint32_t)s_bs; else bs1 = (uint32_t)s_bs;
    __syncthreads();
  }

  bool     predv[8];
  uint64_t keyv[8];
  uint32_t lposv[8];
  int      bv[8];
  int nt = 0;
  for (int base = start; base < end; base += 1024, nt++) {
    int n = base + t;
    bool pred = false; int b = 0; uint64_t key = 0ull; uint32_t lp = 0u;
    if (n < end) {
      float sc = scores[n];
      if (sc > 0.5f * NEGF) {
        b = bix[n];
        uint32_t bs = (b == b0) ? bs0 : bs1;
        if ((uint32_t)score_bin(sc) >= bs) {
          pred = true;
          key = ((uint64_t)orderf(sc) << 32) | (uint64_t)(uint32_t)(~(uint32_t)n);
          lp = atomicAdd(&lcnt[b], 1u);
        }
      }
    }
    predv[nt] = pred; keyv[nt] = key; lposv[nt] = lp; bv[nt] = b;
  }
  __syncthreads();
  if (t < 8) {
    uint32_t c = lcnt[t];
    lbase[t] = c ? atomicAdd(&cnt[t], c) : 0u;
  }
  __syncthreads();
  for (int k = 0; k < nt; k++) {
    if (predv[k]) {
      uint32_t pos = lbase[bv[k]] + lposv[k];
      if (pos < CAP) cand[(size_t)bv[k] * CAP + pos] = keyv[k];
    }
  }
}

// Partial rank-by-count; each (b,ic,js) block writes its partial rank slice.
__global__ void __launch_bounds__(256) k_rank(const uint64_t* __restrict__ cand,
                                              const uint32_t* __restrict__ cnt,
                                              uint32_t* __restrict__ prank) {
  int blk = blockIdx.x;
  int js = blk % JSPLIT;
  int ic = (blk / JSPLIT) % 32;
  int b  = blk / (JSPLIT * 32);
  int t = threadIdx.x;
  int C = (int)min(cnt[b], (uint32_t)CAP);
  if (ic * 256 >= C) return;
  const uint64_t* g = cand + (size_t)b * CAP;
  int i = ic * 256 + t;
  uint64_t ki = (i < C) ? g[i] : 0ull;

  int q = (C + JSPLIT - 1) / JSPLIT;
  int j0 = js * q;
  int j1 = j0 + q < C ? j0 + q : C;

  __shared__ uint64_t tile[1024];
  int rank = 0;
  for (int base = j0; base < j1; base += 1024) {
#pragma unroll
    for (int u = 0; u < 4; u++) {
      int j = base + u * 256 + t;
      tile[u * 256 + t] = (j < j1) ? g[j] : 0ull;
    }
    __syncthreads();
    int lim = j1 - base < 1024 ? j1 - base : 1024;
    const ulonglong2* t2 = (const ulonglong2*)tile;
    int pairs = lim >> 1;
    int jj = 0;
    for (; jj + 4 <= pairs; jj += 4) {
      ulonglong2 v0 = t2[jj + 0], v1 = t2[jj + 1];
      ulonglong2 v2 = t2[jj + 2], v3 = t2[jj + 3];
      rank += (v0.x > ki) ? 1 : 0; rank += (v0.y > ki) ? 1 : 0;
      rank += (v1.x > ki) ? 1 : 0; rank += (v1.y > ki) ? 1 : 0;
      rank += (v2.x > ki) ? 1 : 0; rank += (v2.y > ki) ? 1 : 0;
      rank += (v3.x > ki) ? 1 : 0; rank += (v3.y > ki) ? 1 : 0;
    }
    for (; jj < pairs; jj++) {
      ulonglong2 v = t2[jj];
      rank += (v.x > ki) ? 1 : 0; rank += (v.y > ki) ? 1 : 0;
    }
    if (lim & 1) rank += (tile[lim - 1] > ki) ? 1 : 0;
    __syncthreads();
  }
  if (i < C) prank[((size_t)b * JSPLIT + js) * CAP + i] = (uint32_t)rank;
}

// Fused place + gather: sums the JSPLIT partial ranks, then decodes the box
// directly into row=rank (f64 + f32 mirrors).
__global__ void __launch_bounds__(256) k_place_gather(
    const uint64_t* __restrict__ cand, const uint32_t* __restrict__ cnt,
    const uint32_t* __restrict__ prank,
    const float* __restrict__ anchors, const float* __restrict__ deltas,
    const int* __restrict__ isz,
    double* __restrict__ tbox, double* __restrict__ tarea,
    float4* __restrict__ tboxf, float* __restrict__ tareaf,
    int* __restrict__ top_n, int* __restrict__ Cnum, int B) {
  int idx = blockIdx.x * blockDim.x + threadIdx.x;
  if (idx >= B * CAP) return;
  int b = idx / CAP, i = idx % CAP;
  int C = (int)min(cnt[b], (uint32_t)CAP);
  if (i == 0) Cnum[b] = C < PRE_K ? C : PRE_K;
  if (i >= C) return;
  uint32_t rank = 0;
#pragma unroll
  for (int js = 0; js < JSPLIT; js++)
    rank += prank[((size_t)b * JSPLIT + js) * CAP + i];
  if (rank >= PRE_K) return;
  int n = (int)(~(uint32_t)(cand[idx] & 0xFFFFFFFFull));
  double x1, y1, x2, y2; bool valid;
  decode_box(anchors, deltas, isz, n, b, x1, y1, x2, y2, valid);
  size_t row = (size_t)b * ROWS + rank;
  tbox[row * 4 + 0] = x1;
  tbox[row * 4 + 1] = y1;
  tbox[row * 4 + 2] = x2;
  tbox[row * 4 + 3] = y2;
  double ar = (x2 - x1) * (y2 - y1);
  tarea[row] = ar;
  tboxf[row] = make_float4((float)x1, (float)y1, (float)x2, (float)y2);
  tareaf[row] = (float)ar;
  top_n[b * PRE_K + rank] = n;
}

// Suppression bit tiles, FULL upper triangle (rc <= cc), ballot-free:
// lane = ROW within the rc chunk; cols of the cc chunk broadcast from LDS.
// Each lane builds its row's 64-bit word locally and stores it directly.
// Chunk-major transposed layout: maskT[((b*CH + cc)*ROWS + row)*2 + w].
__global__ void __launch_bounds__(64) k_iou_mat(const float4* __restrict__ tboxf,
                                                const float* __restrict__ tareaf,
                                                const double* __restrict__ tbox,
                                                const double* __restrict__ tarea,
                                                const int* __restrict__ Cnum,
                                                uint32_t* __restrict__ maskT) {
  int rc = blockIdx.x;
  int cc = blockIdx.y;
  int b  = blockIdx.z;
  if (rc > cc) return;
  int C = Cnum[b];
  if (cc * 64 >= C) return;   // rc <= cc, so rc*64 < C too
  int lane = threadIdx.x;
  size_t bb = (size_t)b * ROWS;

  float4 rb4 = tboxf[bb + (size_t)rc * 64 + lane];
  float  sra = 0.7f * tareaf[bb + (size_t)rc * 64 + lane];
  __shared__ float4 cbx[64];
  __shared__ float  csa[64];
  cbx[lane] = tboxf[bb + (size_t)cc * 64 + lane];
  csa[lane] = 0.7f * tareaf[bb + (size_t)cc * 64 + lane];
  __syncthreads();

  bool isdiag = (rc == cc);
  uint32_t res0 = 0u, res1 = 0u;

  for (int j = 0; j < 64; j++) {
    float4 c4 = cbx[j];
    float sca = csa[j];
    float iw = fminf(c4.z, rb4.z) - fmaxf(c4.x, rb4.x);
    float ih = fminf(c4.w, rb4.w) - fmaxf(c4.y, rb4.y);
    iw = fmaxf(iw, 0.0f); ih = fmaxf(ih, 0.0f);
    float inter = iw * ih;
    float diff = fmaf(1.7f, inter, -(sra + sca));
    bool gt = isdiag ? (j > lane) : true;
    bool sup = gt && (diff > IOU_EPS);
    if (gt && !sup && diff > -IOU_EPS) {
      sup = iou_exact(tbox, tarea, bb + (size_t)rc * 64 + lane,
                      bb + (size_t)cc * 64 + j);
    }
    if (sup) { if (j < 32) res0 |= 1u << j; else res1 |= 1u << (j & 31); }
  }
  uint2* seg = (uint2*)(maskT + (((size_t)b * CH + cc) * ROWS + (size_t)rc * 64) * 2);
  seg[lane] = make_uint2(res0, res1);
}

// Greedy resolve with forward-accumulated 64-bit suppression per chunk.
// acc[cc] = OR over already-kept rows j of mask(j, cc).
// Coverage of a row kept at iteration k over all cc > k:
//   cc = k+1, k+2 : wave0 ballots at iter k using DEPTH-2 parity-prefetched
//                   band words (issued at iter k-2 -> ~2 barrier intervals
//                   of latency slack, NOT drained at barriers)
//   cc >= k+3     : waves 1-3 ISSUE loads at iter k+1 (static-indexed regs),
//                   COMMIT via LDS atomicOr at iter k+2; read at >= k+3.
// Per-chunk barrier drains LDS only (wg_barrier_lds) so global prefetch
// loads stay in flight across barriers. ~3 KB LDS.
__global__ void __launch_bounds__(256) k_nms_reduce(const uint32_t* __restrict__ maskT,
                                                    const double* __restrict__ tbox,
                                                    const int* __restrict__ Cnum,
                                                    const int* __restrict__ top_n,
                                                    const float* __restrict__ logits,
                                                    const float* __restrict__ deltas,
                                                    float* __restrict__ out, int B) {
  int b = blockIdx.x, t = threadIdx.x;
  int wave = t >> 6, lane = t & 63;
  int C = Cnum[b];
  int nch = (C + 63) >> 6;
  const uint2* Mb = (const uint2*)(maskT + (size_t)b * CH * ROWS * 2);
  size_t bb = (size_t)b * ROWS;

  __shared__ uint32_t acc[CH][2];      // forward-accumulated suppression bits
  __shared__ uint16_t kept[POST_K];    // kept rows, greedy order
  __shared__ uint16_t pend[2][64];     // rows kept at iteration c, parity c&1
  __shared__ int      npend[2];
  __shared__ uint64_t s_kept;

  for (int i = t; i < CH * 2; i += 256) ((uint32_t*)acc)[i] = 0u;
  if (t < 2) npend[t] = 0;
  __syncthreads();

  // wave0 depth-2 prefetch register sets (parity: A = even chunks, B = odd).
  // For chunk c (rows base=c*64): dg = mask(rows_c, col c) [diag],
  // pf = mask(rows_c, col c+1), qf = mask(rows_c, col c+2).
  uint2 dgA = make_uint2(0u,0u), pfA = make_uint2(0u,0u), qfA = make_uint2(0u,0u);
  uint2 dgB = make_uint2(0u,0u), pfB = make_uint2(0u,0u), qfB = make_uint2(0u,0u);
  if (wave == 0) {
    if (nch > 0) {
      dgA = Mb[(size_t)0 * ROWS + 0 + lane];
      if (nch > 1) pfA = Mb[(size_t)1 * ROWS + 0 + lane];
      if (nch > 2) qfA = Mb[(size_t)2 * ROWS + 0 + lane];
    }
    if (nch > 1) {
      dgB = Mb[(size_t)1 * ROWS + 64 + lane];
      if (nch > 2) pfB = Mb[(size_t)2 * ROWS + 64 + lane];
      if (nch > 3) qfB = Mb[(size_t)3 * ROWS + 64 + lane];
    }
  }

  // lazy pipeline state (waves 1-3): values loaded last iteration
  uint2 lz[KREG];
#pragma unroll
  for (int u = 0; u < KREG; u++) lz[u] = make_uint2(0u, 0u);
  int lz_total = 0, lz_cc0 = 0, lz_span = 1;

  int nkept = 0;
  for (int c = 0; c < nch; c++) {
    if (wave == 0) {
      // ---- select prefetched words for chunk c (parity) ----
      uint2 dgv, pfv, qfv;
      if (c & 1) { dgv = dgB; pfv = pfB; qfv = qfB; }
      else       { dgv = dgA; pfv = pfA; qfv = qfA; }
      // ---- resolve chunk c (acc[c] complete by barrier discipline) ----
      int base = c << 6;
      uint64_t sup = (uint64_t)acc[c][0] | ((uint64_t)acc[c][1] << 32);
      int rem = C - base;
      if (rem < 64) sup |= ~((1ull << rem) - 1ull);
      uint64_t diag = (uint64_t)dgv.x | ((uint64_t)dgv.y << 32);
      uint64_t keptMask = 0ull;
      uint64_t alive = ~sup;
      uint64_t m = alive;
      while (m) {
        int i = __builtin_ctzll(m);
        keptMask |= 1ull << i;
        uint64_t d = (uint64_t)__shfl((long long)diag, i, 64);
        sup |= d | (1ull << i);
        m = alive & ~sup;
      }
      int allowed = POST_K - nkept;
      int pc2 = __popcll(keptMask);
      while (pc2 > allowed) {
        keptMask &= ~(1ull << (63 - __builtin_clzll(keptMask)));
        pc2--;
      }
      if (lane == 0) { s_kept = keptMask; npend[c & 1] = pc2; }
      bool mine = (keptMask >> lane) & 1ull;
      if (mine) {
        int pfx = __popcll(keptMask & ((1ull << lane) - 1ull));
        kept[nkept + pfx] = (uint16_t)(base + lane);
        pend[c & 1][pfx] = (uint16_t)(base + lane);
      }
      // ---- zero-latency ballots: kept rows of chunk c -> acc[c+1], acc[c+2] --
      if (c + 1 < nch) {
        uint32_t v0 = mine ? pfv.x : 0u, v1 = mine ? pfv.y : 0u;
        uint32_t w0 = mine ? qfv.x : 0u, w1 = mine ? qfv.y : 0u;
#pragma unroll
        for (int off = 32; off > 0; off >>= 1) {
          v0 |= (uint32_t)__shfl_xor((int)v0, off, 64);
          v1 |= (uint32_t)__shfl_xor((int)v1, off, 64);
          w0 |= (uint32_t)__shfl_xor((int)w0, off, 64);
          w1 |= (uint32_t)__shfl_xor((int)w1, off, 64);
        }
        if (lane == 0) {
          if (v0) atomicOr(&acc[c + 1][0], v0);
          if (v1) atomicOr(&acc[c + 1][1], v1);
          if (c + 2 < nch) {
            if (w0) atomicOr(&acc[c + 2][0], w0);
            if (w1) atomicOr(&acc[c + 2][1], w1);
          }
        }
      }
      // ---- issue depth-2 prefetch for chunk c+2 (same parity set) ----
      if (c + 2 < nch) {
        int cn = c + 2;
        int nb = cn << 6;
        uint2 d2 = Mb[(size_t)cn * ROWS + nb + lane];
        uint2 p2 = (cn + 1 < nch) ? Mb[(size_t)(cn + 1) * ROWS + nb + lane]
                                  : make_uint2(0u, 0u);
        uint2 q2 = (cn + 2 < nch) ? Mb[(size_t)(cn + 2) * ROWS + nb + lane]
                                  : make_uint2(0u, 0u);
        if (c & 1) { dgB = d2; pfB = p2; qfB = q2; }
        else       { dgA = d2; pfA = p2; qfA = q2; }
      }
    } else {
      // ---- (1) COMMIT values loaded last iteration (targets cc >= c+1) ----
      if (lz_total > 0) {
#pragma unroll
        for (int u = 0; u < KREG; u++) {
          int it = (t - 64) + u * 192;
          if (it < lz_total) {
            int pi = it / lz_span;
            int cc = lz_cc0 + (it - pi * lz_span);
            if (lz[u].x) atomicOr(&acc[cc][0], lz[u].x);
            if (lz[u].y) atomicOr(&acc[cc][1], lz[u].y);
          }
        }
      }
      // ---- (2) ISSUE loads for rows kept at iteration c-1 (cc >= c+2) ----
      int np = (c >= 1) ? npend[(c - 1) & 1] : 0;
      int cc0 = c + 2;
      int span = nch - cc0;
      if (np > 0 && span > 0) {
        int total = np * span;
#pragma unroll
        for (int u = 0; u < KREG; u++) {
          int it = (t - 64) + u * 192;
          uint2 v = make_uint2(0u, 0u);
          if (it < total) {
            int pi = it / span;
            int cc = cc0 + (it - pi * span);
            int row = (int)pend[(c - 1) & 1][pi];
            v = Mb[(size_t)cc * ROWS + row];
          }
          lz[u] = v;
        }
        // overflow beyond KREG slots: immediate load+commit (rare)
        for (int it = (t - 64) + KREG * 192; it < total; it += 192) {
          int pi = it / span;
          int cc = cc0 + (it - pi * span);
          int row = (int)pend[(c - 1) & 1][pi];
          uint2 v = Mb[(size_t)cc * ROWS + row];
          if (v.x) atomicOr(&acc[cc][0], v.x);
          if (v.y) atomicOr(&acc[cc][1], v.y);
        }
        lz_total = total < KREG * 192 ? total : KREG * 192;
        lz_cc0 = cc0; lz_span = span;
      } else {
        lz_total = 0;
      }
    }
    wg_barrier_lds();   // LDS drained; global prefetches stay in flight

    int pc = __popcll(s_kept);
    nkept += pc;
    if (nkept >= POST_K) break;
  }

  // ---- fused output: block writes its batch's POST_K rows ----
  __syncthreads();
  int M_out = B * POST_K;
  for (int s2 = t; s2 < POST_K; s2 += 256) {
    float p0 = 0.f, p1 = 0.f, p2 = 0.f, p3 = 0.f;
    float ob = 0.f, d0f = 0.f, d1f = 0.f, d2f = 0.f, d3f = 0.f;
    float bi = -1.0f, okv = 0.0f;
    if (s2 < nkept) {
      int j = (int)kept[s2];
      int n = top_n[b * PRE_K + j];
      const double* p = &tbox[(bb + j) * 4];
      p0 = (float)p[0]; p1 = (float)p[1]; p2 = (float)p[2]; p3 = (float)p[3];
      ob = logits[n];
      d0f = deltas[4 * n + 0]; d1f = deltas[4 * n + 1];
      d2f = deltas[4 * n + 2]; d3f = deltas[4 * n + 3];
      bi = (float)b; okv = 1.0f;
    }
    int idx = b * POST_K + s2;
    out[idx * 4 + 0] = p0;
    out[idx * 4 + 1] = p1;
    out[idx * 4 + 2] = p2;
    out[idx * 4 + 3] = p3;
    out[4 * M_out + idx] = bi;
    out[5 * M_out + idx] = ob;
    out[6 * M_out + idx * 4 + 0] = d0f;
    out[6 * M_out + idx * 4 + 1] = d1f;
    out[6 * M_out + idx * 4 + 2] = d2f;
    out[6 * M_out + idx * 4 + 3] = d3f;
    out[10 * M_out + idx] = okv;
  }
}

// ---- launch -----------------------------------------------------------------

extern "C" void kernel_launch(void* const* d_in, const int* in_sizes, int n_in,
                              void* d_out, int out_size, void* d_ws, size_t ws_size,
                              hipStream_t stream) {
  const float* anchors = (const float*)d_in[0];
  const int*   bix     = (const int*)d_in[1];
  const int*   isz     = (const int*)d_in[2];
  const float* logits  = (const float*)d_in[3];
  const float* deltas  = (const float*)d_in[4];
  float* out = (float*)d_out;

  int N = in_sizes[1];
  int B = in_sizes[2] / 2;

  uintptr_t p = (uintptr_t)d_ws;
  double*   tbox   = (double*)p;    p += (size_t)B * ROWS * 4 * sizeof(double);
  double*   tarea  = (double*)p;    p += (size_t)B * ROWS * sizeof(double);
  uint64_t* cand   = (uint64_t*)p;  p += (size_t)B * CAP * sizeof(uint64_t);
  float*    scores = (float*)p;     p += (size_t)N * sizeof(float);
  uint32_t* hist   = (uint32_t*)p;  p += (size_t)B * BINS * sizeof(uint32_t);
  uint32_t* cnt    = (uint32_t*)p;  p += (size_t)B * sizeof(uint32_t);   // adjacent to hist
  uint32_t* prank  = (uint32_t*)p;  p += (size_t)B * JSPLIT * CAP * sizeof(uint32_t);
  int*      top_n    = (int*)p;     p += (size_t)B * PRE_K * sizeof(int);
  int*      Cnum     = (int*)p;      p += (size_t)B * sizeof(int);
  p = (p + 255) & ~(uintptr_t)255;
  uint32_t* maskT    = (uint32_t*)p; p += (size_t)B * CH * ROWS * 2 * sizeof(uint32_t);
  // f32 box mirror overlays `scores` (dead after k_compact)
  float4*   tboxf  = (float4*)scores;
  float*    tareaf = (float*)(scores + (size_t)B * ROWS * 4);
  (void)ws_size; (void)n_in; (void)out_size;

  hipMemsetAsync(hist, 0, (size_t)(B * BINS + B) * sizeof(uint32_t), stream);
  k_score<<<(N + 4095) / 4096, 256, 0, stream>>>(anchors, bix, isz, logits, deltas,
                                                 scores, hist, N);
  k_compact<<<(N + 8191) / 8192, 1024, 0, stream>>>(scores, bix, hist, cnt, cand, N);
  k_rank<<<B * 32 * JSPLIT, 256, 0, stream>>>(cand, cnt, prank);
  k_place_gather<<<(B * CAP + 255) / 256, 256, 0, stream>>>(cand, cnt, prank,
                                                            anchors, deltas, isz,
                                                            tbox, tarea, tboxf,
                                                            tareaf, top_n, Cnum, B);
  dim3 iou_grid(CH, CH, B);
  k_iou_mat<<<iou_grid, 64, 0, stream>>>(tboxf, tareaf, tbox, tarea, Cnum, maskT);
  k_nms_reduce<<<B, 256, 0, stream>>>(maskT, tbox, Cnum, top_n, logits, deltas,
                                      out, B);
}